// Round 1
// 893.127 us; speedup vs baseline: 1.1205x; 1.1205x over previous
//
#include <hip/hip_runtime.h>
#include <hip/hip_bf16.h>
#include <math.h>

// Problem constants (BlenderbotDecoderLayer prefill)
#define TB   4
#define TS   128
#define TD   2560
#define TH   32
#define THD  80
#define TFFN 10240
#define TDEC 256
#define TM   (TB * TS)            // 512 rows
#define CACHE_N ((size_t)TB * TH * TDEC * THD)  // 2,621,440

using short8  = __attribute__((ext_vector_type(8))) short;
using sshort4 = __attribute__((ext_vector_type(4))) short;
using floatx4 = __attribute__((ext_vector_type(4))) float;

__device__ __forceinline__ short f2bf(float f) {
  unsigned u = __builtin_bit_cast(unsigned, f);
  u += 0x7fff + ((u >> 16) & 1);           // RNE
  return (short)(u >> 16);
}
__device__ __forceinline__ float bf2f(short s) {
  unsigned u = ((unsigned)(unsigned short)s) << 16;
  return __builtin_bit_cast(float, u);
}

// ---------------------------------------------------------------------------
// Fused multi-segment split-K GEMM with register double-buffering.
//   partial[z][M,N] = A(bf16)[M,Kc] @ B(fp32, [Kc,N])   (k-chunk z)
// 128x128 tile, BK=32, 4 waves 2x2, wave = 4x4 MFMA 16x16x32_bf16.
// blockIdx.x = seg*tilesPerSeg + n-tile; blockIdx.y = m-tile; blockIdx.z = k-chunk.
// All epilogues (bias/scatter/GELU) live in the combine kernels now -- split-K
// raises grid to 640-960 blocks (2.5-3.75 blocks/CU; 4x40KB LDS = exactly 160KB)
// so barrier/VMEM latency is hidden by co-resident blocks.
// ---------------------------------------------------------------------------
struct GArgs {
  const short* A[3];
  const float* B[3];
  float*       outf[3];   // partial buffer, z-slices of TM*N
  int tilesPerSeg;
  int N;      // columns per segment
  int lda;    // full K of A
  int Kc;     // K-chunk per blockIdx.z
};

__device__ __forceinline__ void stage_load(const short* __restrict__ A,
                                           const float* __restrict__ B,
                                           int lda, int N, int m0, int n0, int k0,
                                           int tid, short8 ra[2], float rb[16])
{
  const int cb = (tid & 3) * 8;
  const int rr = tid >> 2;
#pragma unroll
  for (int it = 0; it < 2; ++it)
    ra[it] = *(const short8*)(A + (size_t)(m0 + rr + it * 64) * lda + k0 + cb);
  const int n  = tid & 127;
  const int kg = (tid >> 7) * 16;
  const float* bp = B + (size_t)(k0 + kg) * N + n0 + n;
#pragma unroll
  for (int j = 0; j < 16; ++j)
    rb[j] = bp[(size_t)j * N];
}

__device__ __forceinline__ void stage_commit(short* __restrict__ As, short* __restrict__ Bs,
                                             int tid, const short8 ra[2], const float rb[16])
{
  const int cb = (tid & 3) * 8;
  const int rr = tid >> 2;
#pragma unroll
  for (int it = 0; it < 2; ++it)
    *(short8*)(&As[(rr + it * 64) * 40 + cb]) = ra[it];
  const int n  = tid & 127;
  const int kg = (tid >> 7) * 16;
  short8 lo, hi;
#pragma unroll
  for (int j = 0; j < 8; ++j) { lo[j] = f2bf(rb[j]); hi[j] = f2bf(rb[8 + j]); }
  *(short8*)(&Bs[n * 40 + kg])     = lo;
  *(short8*)(&Bs[n * 40 + kg + 8]) = hi;
}

__global__ __launch_bounds__(256, 2)
void gemmF(GArgs g)
{
  __shared__ short As[2][128 * 40];   // 10240 B each
  __shared__ short Bs[2][128 * 40];   // total 40960 B

  const int seg = blockIdx.x / g.tilesPerSeg;
  const int tx  = blockIdx.x % g.tilesPerSeg;
  const short* A = g.A[seg];
  const float* B = g.B[seg];
  const int N = g.N, lda = g.lda;
  const int m0 = blockIdx.y * 128;
  const int n0 = tx * 128;
  const int z  = blockIdx.z;
  const int k0base = z * g.Kc;
  const int nk = g.Kc / 32;

  const int tid = threadIdx.x;
  const int lane = tid & 63;
  const int wv = tid >> 6;
  const int wm = (wv >> 1) * 64;
  const int wn = (wv & 1) * 64;
  const int lr = lane & 15;
  const int lq = lane >> 4;

  floatx4 acc[4][4];
#pragma unroll
  for (int i = 0; i < 4; ++i)
#pragma unroll
    for (int j = 0; j < 4; ++j)
      acc[i][j] = floatx4{0.f, 0.f, 0.f, 0.f};

  short8 ra[2]; float rb[16];
  stage_load(A, B, lda, N, m0, n0, k0base, tid, ra, rb);
  stage_commit(As[0], Bs[0], tid, ra, rb);
  __syncthreads();

  for (int ki = 0; ki < nk; ++ki) {
    const int cur = ki & 1;
    const bool more = (ki + 1 < nk);
    if (more)
      stage_load(A, B, lda, N, m0, n0, k0base + (ki + 1) * 32, tid, ra, rb);

    short8 af[4], bfr[4];
#pragma unroll
    for (int t = 0; t < 4; ++t)
      af[t] = *(const short8*)(&As[cur][(wm + t * 16 + lr) * 40 + lq * 8]);
#pragma unroll
    for (int t = 0; t < 4; ++t)
      bfr[t] = *(const short8*)(&Bs[cur][(wn + t * 16 + lr) * 40 + lq * 8]);
#pragma unroll
    for (int tm = 0; tm < 4; ++tm)
#pragma unroll
      for (int tn = 0; tn < 4; ++tn)
        acc[tm][tn] = __builtin_amdgcn_mfma_f32_16x16x32_bf16(af[tm], bfr[tn],
                                                              acc[tm][tn], 0, 0, 0);
    if (more)
      stage_commit(As[cur ^ 1], Bs[cur ^ 1], tid, ra, rb);
    __syncthreads();
  }

  // Epilogue: raw partial write (combine kernels do bias/activation/scatter)
  float* outf = g.outf[seg];
#pragma unroll
  for (int tm = 0; tm < 4; ++tm) {
#pragma unroll
    for (int tn = 0; tn < 4; ++tn) {
      const int col = n0 + wn + tn * 16 + lr;
#pragma unroll
      for (int r = 0; r < 4; ++r) {
        const int row = m0 + wm + tm * 16 + lq * 4 + r;
        outf[(size_t)z * TM * N + (size_t)row * N + col] = acc[tm][tn][r];
      }
    }
  }
}

// ---------------------------------------------------------------------------
// QKV combine: sum Z split-K partials (3 segments of TM x TD each), add bias,
// route: seg 0 -> qbuf (plain), seg 1/2 -> K/V cache scatter [b,h,s,hd].
// ---------------------------------------------------------------------------
template<int Z>
__global__ void qkv_combine_kernel(const float* __restrict__ p,
                                   const float* __restrict__ bq,
                                   const float* __restrict__ bk,
                                   const float* __restrict__ bv,
                                   float* __restrict__ qbuf,
                                   float* __restrict__ sk,
                                   float* __restrict__ sv)
{
  const int i4 = blockIdx.x * 256 + threadIdx.x;     // over TM * 7680 / 4
  const int row = i4 / 1920;
  const int c4  = i4 - row * 1920;
  const int col = c4 * 4;
  const int seg = (col >= 2 * TD) ? 2 : (col >= TD ? 1 : 0);
  const int c   = col - seg * TD;
  const float* base = p + (size_t)seg * ((size_t)Z * TM * TD) + (size_t)row * TD + c;
  float4 v = *(const float4*)base;
#pragma unroll
  for (int zz = 1; zz < Z; ++zz) {
    float4 t = *(const float4*)(base + (size_t)zz * TM * TD);
    v.x += t.x; v.y += t.y; v.z += t.z; v.w += t.w;
  }
  const float* bias = (seg == 0) ? bq : (seg == 1 ? bk : bv);
  float4 b4 = *(const float4*)(bias + c);
  v.x += b4.x; v.y += b4.y; v.z += b4.z; v.w += b4.w;
  if (seg == 0) {
    *(float4*)(qbuf + (size_t)row * TD + c) = v;
  } else {
    const int hh = c / THD, hd = c % THD;
    const int b = row >> 7, sI = row & 127;
    float* dst = (seg == 1) ? sk : sv;
    *(float4*)(dst + (((size_t)(b * TH + hh) * TDEC + sI) * THD + hd)) = v;
  }
}

// ---------------------------------------------------------------------------
// FC1 combine: sum Z partials + bias, exact GELU, write bf16.
// ---------------------------------------------------------------------------
template<int Z>
__global__ void fc1_gelu_kernel(const float* __restrict__ p,
                                const float* __restrict__ bias,
                                short* __restrict__ out)
{
  const int i4 = blockIdx.x * 256 + threadIdx.x;   // over TM*TFFN/4
  const int row = i4 / (TFFN / 4);
  const int c4  = i4 - row * (TFFN / 4);
  const int col = c4 * 4;
  const size_t idx = (size_t)row * TFFN + col;
  float4 v = *(const float4*)(p + idx);
#pragma unroll
  for (int zz = 1; zz < Z; ++zz) {
    float4 t = *(const float4*)(p + (size_t)zz * TM * TFFN + idx);
    v.x += t.x; v.y += t.y; v.z += t.z; v.w += t.w;
  }
  float4 b4 = *(const float4*)(bias + col);
  v.x += b4.x; v.y += b4.y; v.z += b4.z; v.w += b4.w;
  sshort4 o;
  o[0] = f2bf(0.5f * v.x * (1.0f + erff(v.x * 0.70710678118654752f)));
  o[1] = f2bf(0.5f * v.y * (1.0f + erff(v.y * 0.70710678118654752f)));
  o[2] = f2bf(0.5f * v.z * (1.0f + erff(v.z * 0.70710678118654752f)));
  o[3] = f2bf(0.5f * v.w * (1.0f + erff(v.w * 0.70710678118654752f)));
  *(sshort4*)(out + idx) = o;
}

// ---------------------------------------------------------------------------
// Attention: one block per (b,h, 64-q-row tile). K/V bf16 in LDS, scores in
// registers (4 lanes per q-row), softmax via shfl, P bf16 reusing Q LDS.
// ---------------------------------------------------------------------------
template<bool CAUSAL>
__global__ __launch_bounds__(256, 2)
void attn_kernel(const float* __restrict__ q, const float* __restrict__ kc,
                 const float* __restrict__ vc, short* __restrict__ ob)
{
  __shared__ short kb[TS * THD];
  __shared__ short vb[TS * THD];
  __shared__ float qf[64 * 84];
  short* pb = (short*)qf;

  const int tid = threadIdx.x;
  const int bh = blockIdx.x;
  const int b = bh >> 5, h = bh & 31;
  const int r0 = blockIdx.y * 64;

  const size_t cbase = (size_t)bh * TDEC * THD;
  for (int idx = tid; idx < TS * THD; idx += 256) {
    kb[idx] = f2bf(kc[cbase + idx]);
    vb[idx] = f2bf(vc[cbase + idx]);
  }
  for (int idx = tid; idx < 64 * THD; idx += 256) {
    int r = idx / THD, d = idx - r * THD;
    qf[r * 84 + d] = q[(size_t)(b * TS + r0 + r) * TD + h * THD + d];
  }
  __syncthreads();

  const int r = tid >> 2;
  const int quarter = tid & 3;
  const int qi = r0 + r;

  float sc[32];
#pragma unroll 1
  for (int jj = 0; jj < 32; ++jj) {
    int j = quarter + jj * 4;
    if (CAUSAL && j > qi) { sc[jj] = -1e30f; continue; }
    float a = 0.f;
#pragma unroll 8
    for (int d = 0; d < THD; ++d)
      a += qf[r * 84 + d] * bf2f(kb[j * THD + d]);
    sc[jj] = a * 0.11180339887498949f;
  }

  float mx = -1e30f;
#pragma unroll
  for (int jj = 0; jj < 32; ++jj) mx = fmaxf(mx, sc[jj]);
  mx = fmaxf(mx, __shfl_xor(mx, 1));
  mx = fmaxf(mx, __shfl_xor(mx, 2));
  float sum = 0.f;
#pragma unroll
  for (int jj = 0; jj < 32; ++jj) { sc[jj] = __expf(sc[jj] - mx); sum += sc[jj]; }
  sum += __shfl_xor(sum, 1);
  sum += __shfl_xor(sum, 2);
  const float rinv = 1.0f / sum;

  __syncthreads();
#pragma unroll
  for (int jj = 0; jj < 32; ++jj)
    pb[r * TS + quarter + jj * 4] = f2bf(sc[jj] * rinv);
  __syncthreads();

  for (int it = 0; it < 20; ++it) {
    int idx = tid + it * 256;
    int rr = idx / THD, d = idx - rr * THD;
    float a = 0.f;
#pragma unroll 8
    for (int j = 0; j < TS; ++j)
      a += bf2f(pb[rr * TS + j]) * bf2f(vb[j * THD + d]);
    ob[(size_t)(b * TS + r0 + rr) * TD + h * THD + d] = f2bf(a);
  }
}

// ---------------------------------------------------------------------------
// LayerNorm variants
// ---------------------------------------------------------------------------
__global__ __launch_bounds__(256, 4)
void ln_kernel(const float* __restrict__ x, const float* __restrict__ g,
               const float* __restrict__ bb, short* __restrict__ out)
{
  const int row = blockIdx.x;
  const float* xr = x + (size_t)row * TD;
  const int tid = threadIdx.x;
  float vals[10];
  float s = 0.f, ss = 0.f;
#pragma unroll
  for (int it = 0; it < 10; ++it) {
    float v = xr[tid + it * 256];
    vals[it] = v; s += v; ss += v * v;
  }
#pragma unroll
  for (int o = 32; o > 0; o >>= 1) { s += __shfl_xor(s, o); ss += __shfl_xor(ss, o); }
  __shared__ float red[8];
  const int wv = tid >> 6, lane = tid & 63;
  if (lane == 0) { red[wv] = s; red[wv + 4] = ss; }
  __syncthreads();
  s  = red[0] + red[1] + red[2] + red[3];
  ss = red[4] + red[5] + red[6] + red[7];
  const float mu = s * (1.0f / TD);
  const float rstd = rsqrtf(ss * (1.0f / TD) - mu * mu + 1e-5f);
  short* orow = out + (size_t)row * TD;
#pragma unroll
  for (int it = 0; it < 10; ++it) {
    int i = tid + it * 256;
    orow[i] = f2bf((vals[it] - mu) * rstd * g[i] + bb[i]);
  }
}

// x_next = xin + sum_{zz<Z} p[zz] + obias; write x_next (fp32) and LN(x_next) (bf16)
template<int Z>
__global__ __launch_bounds__(256, 4)
void ln_fuse_kernel(const float* __restrict__ xin, const float* __restrict__ p,
                    const float* __restrict__ obias,
                    const float* __restrict__ g, const float* __restrict__ bb,
                    short* __restrict__ hout, float* __restrict__ xout)
{
  const int row = blockIdx.x;
  const int tid = threadIdx.x;
  const size_t base = (size_t)row * TD;
  float vals[10];
  float s = 0.f, ss = 0.f;
#pragma unroll
  for (int it = 0; it < 10; ++it) {
    int i = tid + it * 256;
    float v = xin[base + i] + obias[i];
#pragma unroll
    for (int zz = 0; zz < Z; ++zz)
      v += p[(size_t)zz * TM * TD + base + i];
    vals[it] = v; xout[base + i] = v; s += v; ss += v * v;
  }
#pragma unroll
  for (int o = 32; o > 0; o >>= 1) { s += __shfl_xor(s, o); ss += __shfl_xor(ss, o); }
  __shared__ float red[8];
  const int wv = tid >> 6, lane = tid & 63;
  if (lane == 0) { red[wv] = s; red[wv + 4] = ss; }
  __syncthreads();
  s  = red[0] + red[1] + red[2] + red[3];
  ss = red[4] + red[5] + red[6] + red[7];
  const float mu = s * (1.0f / TD);
  const float rstd = rsqrtf(ss * (1.0f / TD) - mu * mu + 1e-5f);
#pragma unroll
  for (int it = 0; it < 10; ++it) {
    int i = tid + it * 256;
    hout[base + i] = f2bf((vals[it] - mu) * rstd * g[i] + bb[i]);
  }
}

// out = x2 + sum_{zz<Z} p[zz] + bias
template<int Z>
__global__ void fc2_combine_kernel(const float* __restrict__ x2, const float* __restrict__ p,
                                   const float* __restrict__ bias, float* __restrict__ out)
{
  const size_t i = ((size_t)blockIdx.x * 256 + threadIdx.x) * 4;
  const int col = (int)(i % TD);
  float4 v = *(const float4*)(x2 + i);
#pragma unroll
  for (int zz = 0; zz < Z; ++zz) {
    float4 t = *(const float4*)(p + (size_t)zz * TM * TD + i);
    v.x += t.x; v.y += t.y; v.z += t.z; v.w += t.w;
  }
  float4 b4 = *(const float4*)(bias + col);
  v.x += b4.x; v.y += b4.y; v.z += b4.z; v.w += b4.w;
  *(float4*)(out + i) = v;
}

__global__ void cvt_bf16_kernel(const float* __restrict__ in, short* __restrict__ out, int n)
{
  int i = blockIdx.x * 256 + threadIdx.x;
  if (i < n) out[i] = f2bf(in[i]);
}

// Copy cache tail rows (s in [128,256)); float4 granularity.
__global__ void tailcopy_kernel(const float* __restrict__ src, float* __restrict__ dst)
{
  int off4 = blockIdx.x * 256 + threadIdx.x;
  int chunk = blockIdx.y;
  size_t pos = (size_t)chunk * 5120 + 2560 + off4;
  ((float4*)dst)[pos] = ((const float4*)src)[pos];
}

// ---------------------------------------------------------------------------
extern "C" void kernel_launch(void* const* d_in, const int* in_sizes, int n_in,
                              void* d_out, int out_size, void* d_ws, size_t ws_size,
                              hipStream_t stream)
{
  (void)in_sizes; (void)n_in; (void)out_size; (void)ws_size;
  const float* x        = (const float*)d_in[0];
  const float* xa       = (const float*)d_in[1];
  const float* ln1_g    = (const float*)d_in[4];
  const float* ln1_b    = (const float*)d_in[5];
  const float* ln2_g    = (const float*)d_in[6];
  const float* ln2_b    = (const float*)d_in[7];
  const float* ln3_g    = (const float*)d_in[8];
  const float* ln3_b    = (const float*)d_in[9];
  const float* sa_wq    = (const float*)d_in[10];
  const float* sa_wk    = (const float*)d_in[11];
  const float* sa_wv    = (const float*)d_in[12];
  const float* sa_wo    = (const float*)d_in[13];
  const float* sa_bq    = (const float*)d_in[14];
  const float* sa_bk    = (const float*)d_in[15];
  const float* sa_bv    = (const float*)d_in[16];
  const float* sa_bo    = (const float*)d_in[17];
  const float* ca_wq    = (const float*)d_in[18];
  const float* ca_wk    = (const float*)d_in[19];
  const float* ca_wv    = (const float*)d_in[20];
  const float* ca_wo    = (const float*)d_in[21];
  const float* ca_bq    = (const float*)d_in[22];
  const float* ca_bk    = (const float*)d_in[23];
  const float* ca_bv    = (const float*)d_in[24];
  const float* ca_bo    = (const float*)d_in[25];
  const float* cache_sk = (const float*)d_in[26];
  const float* cache_sv = (const float*)d_in[27];
  const float* cache_ck = (const float*)d_in[28];
  const float* cache_cv = (const float*)d_in[29];
  const float* fc1_w    = (const float*)d_in[30];
  const float* fc1_b    = (const float*)d_in[31];
  const float* fc2_w    = (const float*)d_in[32];
  const float* fc2_b    = (const float*)d_in[33];

  float* out_x  = (float*)d_out;
  float* out_sk = out_x + (size_t)TM * TD;
  float* out_sv = out_sk + CACHE_N;
  float* out_ck = out_sv + CACHE_N;
  float* out_cv = out_ck + CACHE_N;

  char* w = (char*)d_ws;
  short* h_b   = (short*)w; w += (size_t)TM * TD * 2;
  short* xa_b  = (short*)w; w += (size_t)TM * TD * 2;
  short* o_b   = (short*)w; w += (size_t)TM * TD * 2;
  short* ffn_b = (short*)w; w += (size_t)TM * TFFN * 2;
  float* qbuf  = (float*)w; w += (size_t)TM * TD * 4;
  float* x1    = (float*)w; w += (size_t)TM * TD * 4;
  float* x2    = (float*)w; w += (size_t)TM * TD * 4;
  float* pbuf  = (float*)w; w += (size_t)TM * TD * 4 * 12;   // 12 z-slices (max: QKV 3 segs x z=4)

  const dim3 blk(256);
  const dim3 gAttn(TB * TH, 2);

  // prep
  cvt_bf16_kernel<<<dim3(TM * TD / 256), blk, 0, stream>>>(xa, xa_b, TM * TD);
  tailcopy_kernel<<<dim3(10, TB * TH), blk, 0, stream>>>(cache_sk, out_sk);
  tailcopy_kernel<<<dim3(10, TB * TH), blk, 0, stream>>>(cache_sv, out_sv);
  tailcopy_kernel<<<dim3(10, TB * TH), blk, 0, stream>>>(cache_ck, out_ck);
  tailcopy_kernel<<<dim3(10, TB * TH), blk, 0, stream>>>(cache_cv, out_cv);

  // ---- self-attention ----
  ln_kernel<<<dim3(TM), blk, 0, stream>>>(x, ln1_g, ln1_b, h_b);
  {
    GArgs a{};
    a.A[0] = h_b; a.B[0] = sa_wq; a.outf[0] = pbuf;
    a.A[1] = h_b; a.B[1] = sa_wk; a.outf[1] = pbuf + (size_t)4 * TM * TD;
    a.A[2] = h_b; a.B[2] = sa_wv; a.outf[2] = pbuf + (size_t)8 * TM * TD;
    a.tilesPerSeg = 20; a.N = TD; a.lda = TD; a.Kc = TD / 4;
    gemmF<<<dim3(60, 4, 4), blk, 0, stream>>>(a);
  }
  qkv_combine_kernel<4><<<dim3(TM * 7680 / 4 / 256), blk, 0, stream>>>(
      pbuf, sa_bq, sa_bk, sa_bv, qbuf, out_sk, out_sv);
  attn_kernel<true><<<gAttn, blk, 0, stream>>>(qbuf, out_sk, out_sv, o_b);
  {
    GArgs a{};
    a.A[0] = o_b; a.B[0] = sa_wo; a.outf[0] = pbuf;
    a.tilesPerSeg = 20; a.N = TD; a.lda = TD; a.Kc = TD / 8;
    gemmF<<<dim3(20, 4, 8), blk, 0, stream>>>(a);
  }
  ln_fuse_kernel<8><<<dim3(TM), blk, 0, stream>>>(x, pbuf, sa_bo, ln2_g, ln2_b, h_b, x1);

  // ---- cross-attention ----
  {
    GArgs a{};
    a.A[0] = h_b;  a.B[0] = ca_wq; a.outf[0] = pbuf;
    a.A[1] = xa_b; a.B[1] = ca_wk; a.outf[1] = pbuf + (size_t)4 * TM * TD;
    a.A[2] = xa_b; a.B[2] = ca_wv; a.outf[2] = pbuf + (size_t)8 * TM * TD;
    a.tilesPerSeg = 20; a.N = TD; a.lda = TD; a.Kc = TD / 4;
    gemmF<<<dim3(60, 4, 4), blk, 0, stream>>>(a);
  }
  qkv_combine_kernel<4><<<dim3(TM * 7680 / 4 / 256), blk, 0, stream>>>(
      pbuf, ca_bq, ca_bk, ca_bv, qbuf, out_ck, out_cv);
  attn_kernel<false><<<gAttn, blk, 0, stream>>>(qbuf, out_ck, out_cv, o_b);
  {
    GArgs a{};
    a.A[0] = o_b; a.B[0] = ca_wo; a.outf[0] = pbuf;
    a.tilesPerSeg = 20; a.N = TD; a.lda = TD; a.Kc = TD / 8;
    gemmF<<<dim3(20, 4, 8), blk, 0, stream>>>(a);
  }
  ln_fuse_kernel<8><<<dim3(TM), blk, 0, stream>>>(x1, pbuf, ca_bo, ln3_g, ln3_b, h_b, x2);

  // ---- MLP ----
  {
    GArgs a{};
    a.A[0] = h_b; a.B[0] = fc1_w; a.outf[0] = pbuf;
    a.tilesPerSeg = 80; a.N = TFFN; a.lda = TD; a.Kc = TD / 2;
    gemmF<<<dim3(80, 4, 2), blk, 0, stream>>>(a);
  }
  fc1_gelu_kernel<2><<<dim3(TM * TFFN / 4 / 256), blk, 0, stream>>>(pbuf, fc1_b, ffn_b);
  {
    GArgs a{};
    a.A[0] = ffn_b; a.B[0] = fc2_w; a.outf[0] = pbuf;
    a.tilesPerSeg = 20; a.N = TD; a.lda = TFFN; a.Kc = TFFN / 8;
    gemmF<<<dim3(20, 4, 8), blk, 0, stream>>>(a);
  }
  fc2_combine_kernel<8><<<dim3(TM * TD / 4 / 256), blk, 0, stream>>>(x2, pbuf, fc2_b, out_x);
}

// Round 2
// 888.054 us; speedup vs baseline: 1.1269x; 1.0057x over previous
//
#include <hip/hip_runtime.h>
#include <hip/hip_bf16.h>
#include <math.h>

// Problem constants (BlenderbotDecoderLayer prefill)
#define TB   4
#define TS   128
#define TD   2560
#define TH   32
#define THD  80
#define TFFN 10240
#define TDEC 256
#define TM   (TB * TS)            // 512 rows
#define CACHE_N ((size_t)TB * TH * TDEC * THD)  // 2,621,440

using short8  = __attribute__((ext_vector_type(8))) short;
using sshort4 = __attribute__((ext_vector_type(4))) short;
using floatx4 = __attribute__((ext_vector_type(4))) float;

__device__ __forceinline__ short f2bf(float f) {
  unsigned u = __builtin_bit_cast(unsigned, f);
  u += 0x7fff + ((u >> 16) & 1);           // RNE
  return (short)(u >> 16);
}
__device__ __forceinline__ float bf2f(short s) {
  unsigned u = ((unsigned)(unsigned short)s) << 16;
  return __builtin_bit_cast(float, u);
}

// ---------------------------------------------------------------------------
// Fused multi-segment split-K GEMM.
//   partial[z][M,N] = A(bf16)[M,Kc] @ B(fp32, [K,N])   (k-chunk z)
// 128x128 tile, BK=32, 4 waves 2x2, wave = 4x4 MFMA 16x16x32_bf16.
// SINGLE 20KB LDS buffer (2 barriers/K-step) + DEPTH-2 register pipeline:
// loads for tile k+2 are in flight while computing tile k, so the vmcnt
// before each commit waits on loads issued a full K-step earlier (~no drain).
// 1-D grid with XCD-sibling swizzle: the 4 m-tiles sharing one B panel
// (same n-tile, z) map to the same XCD for L2 reuse of B.
// LDS rows padded to 40 shorts (80 B): bank-quad (5*row+chunk)%8, conflict-free.
// ---------------------------------------------------------------------------
struct GArgs {
  const short* A[3];
  const float* B[3];
  float*       outf[3];   // partial buffer, z-slices of TM*N
  int tilesPerSeg;
  int nx;     // tilesPerSeg * nsegs (n-tiles across all segments)
  int N;      // columns per segment
  int lda;    // full K of A
  int Kc;     // K-chunk per z (Kc/32 even)
};

__device__ __forceinline__ void stage_load(const short* __restrict__ A,
                                           const float* __restrict__ B,
                                           int lda, int N, int m0, int n0, int k0,
                                           int tid, short8 ra[2], float rb[16])
{
  const int cb = (tid & 3) * 8;
  const int rr = tid >> 2;
#pragma unroll
  for (int it = 0; it < 2; ++it)
    ra[it] = *(const short8*)(A + (size_t)(m0 + rr + it * 64) * lda + k0 + cb);
  const int n  = tid & 127;
  const int kg = (tid >> 7) * 16;
  const float* bp = B + (size_t)(k0 + kg) * N + n0 + n;
#pragma unroll
  for (int j = 0; j < 16; ++j)
    rb[j] = bp[(size_t)j * N];
}

__device__ __forceinline__ void stage_commit(short* __restrict__ As, short* __restrict__ Bs,
                                             int tid, const short8 ra[2], const float rb[16])
{
  const int cb = (tid & 3) * 8;
  const int rr = tid >> 2;
#pragma unroll
  for (int it = 0; it < 2; ++it)
    *(short8*)(&As[(rr + it * 64) * 40 + cb]) = ra[it];
  const int n  = tid & 127;
  const int kg = (tid >> 7) * 16;
  short8 lo, hi;
#pragma unroll
  for (int j = 0; j < 8; ++j) { lo[j] = f2bf(rb[j]); hi[j] = f2bf(rb[8 + j]); }
  *(short8*)(&Bs[n * 40 + kg])     = lo;
  *(short8*)(&Bs[n * 40 + kg + 8]) = hi;
}

__device__ __forceinline__ void compute_step(const short* __restrict__ As,
                                             const short* __restrict__ Bs,
                                             int wm, int wn, int lr, int lq,
                                             floatx4 acc[4][4])
{
  short8 af[4], bfr[4];
#pragma unroll
  for (int t = 0; t < 4; ++t)
    af[t] = *(const short8*)(&As[(wm + t * 16 + lr) * 40 + lq * 8]);
#pragma unroll
  for (int t = 0; t < 4; ++t)
    bfr[t] = *(const short8*)(&Bs[(wn + t * 16 + lr) * 40 + lq * 8]);
#pragma unroll
  for (int tm = 0; tm < 4; ++tm)
#pragma unroll
    for (int tn = 0; tn < 4; ++tn)
      acc[tm][tn] = __builtin_amdgcn_mfma_f32_16x16x32_bf16(af[tm], bfr[tn],
                                                            acc[tm][tn], 0, 0, 0);
}

__global__ __launch_bounds__(256, 3)
void gemmF(GArgs g)
{
  __shared__ short As[128 * 40];   // 10240 B
  __shared__ short Bs[128 * 40];   // total 20480 B

  // XCD-sibling swizzle (grid % 32 == 0): 4 m-siblings -> same XCD.
  const int raw = blockIdx.x;
  const int grp = ((raw >> 5) << 3) | (raw & 7);
  const int my  = (raw >> 3) & 3;
  const int z   = grp / g.nx;
  const int x   = grp - z * g.nx;
  const int seg = x / g.tilesPerSeg;
  const int tx  = x - seg * g.tilesPerSeg;

  const short* A = g.A[seg];
  const float* B = g.B[seg];
  const int N = g.N, lda = g.lda;
  const int m0 = my * 128;
  const int n0 = tx * 128;
  const int k0base = z * g.Kc;
  const int nk = g.Kc / 32;   // even (10..40)

  const int tid = threadIdx.x;
  const int lane = tid & 63;
  const int wv = tid >> 6;
  const int wm = (wv >> 1) * 64;
  const int wn = (wv & 1) * 64;
  const int lr = lane & 15;
  const int lq = lane >> 4;

  floatx4 acc[4][4];
#pragma unroll
  for (int i = 0; i < 4; ++i)
#pragma unroll
    for (int j = 0; j < 4; ++j)
      acc[i][j] = floatx4{0.f, 0.f, 0.f, 0.f};

  short8 raP[2], raF[2];
  float  rbP[16], rbF[16];

  // prologue: tile0 -> LDS; tile1 -> P
  stage_load(A, B, lda, N, m0, n0, k0base, tid, raP, rbP);
  stage_commit(As, Bs, tid, raP, rbP);
  __syncthreads();
  stage_load(A, B, lda, N, m0, n0, k0base + 32, tid, raP, rbP);

  for (int ki = 0; ki < nk; ki += 2) {
    // even step: LDS holds tile ki; P holds tile ki+1; load ki+2 -> F
    if (ki + 2 < nk)
      stage_load(A, B, lda, N, m0, n0, k0base + (ki + 2) * 32, tid, raF, rbF);
    compute_step(As, Bs, wm, wn, lr, lq, acc);
    __syncthreads();
    stage_commit(As, Bs, tid, raP, rbP);        // tile ki+1 -> LDS
    __syncthreads();

    // odd step: LDS holds tile ki+1; F holds tile ki+2; load ki+3 -> P
    if (ki + 3 < nk)
      stage_load(A, B, lda, N, m0, n0, k0base + (ki + 3) * 32, tid, raP, rbP);
    compute_step(As, Bs, wm, wn, lr, lq, acc);
    if (ki + 2 < nk) {
      __syncthreads();
      stage_commit(As, Bs, tid, raF, rbF);      // tile ki+2 -> LDS
      __syncthreads();
    }
  }

  // Epilogue: raw partial write (combine kernels do bias/activation/scatter)
  float* outf = g.outf[seg];
#pragma unroll
  for (int tm = 0; tm < 4; ++tm) {
#pragma unroll
    for (int tn = 0; tn < 4; ++tn) {
      const int col = n0 + wn + tn * 16 + lr;
#pragma unroll
      for (int r = 0; r < 4; ++r) {
        const int row = m0 + wm + tm * 16 + lq * 4 + r;
        outf[(size_t)z * TM * N + (size_t)row * N + col] = acc[tm][tn][r];
      }
    }
  }
}

// ---------------------------------------------------------------------------
// QKV combine: sum Z split-K partials (3 segments of TM x TD each), add bias,
// route: seg 0 -> qbuf (plain), seg 1/2 -> K/V cache scatter [b,h,s,hd].
// ---------------------------------------------------------------------------
template<int Z>
__global__ void qkv_combine_kernel(const float* __restrict__ p,
                                   const float* __restrict__ bq,
                                   const float* __restrict__ bk,
                                   const float* __restrict__ bv,
                                   float* __restrict__ qbuf,
                                   float* __restrict__ sk,
                                   float* __restrict__ sv)
{
  const int i4 = blockIdx.x * 256 + threadIdx.x;     // over TM * 7680 / 4
  const int row = i4 / 1920;
  const int c4  = i4 - row * 1920;
  const int col = c4 * 4;
  const int seg = (col >= 2 * TD) ? 2 : (col >= TD ? 1 : 0);
  const int c   = col - seg * TD;
  const float* base = p + (size_t)seg * ((size_t)Z * TM * TD) + (size_t)row * TD + c;
  float4 v = *(const float4*)base;
#pragma unroll
  for (int zz = 1; zz < Z; ++zz) {
    float4 t = *(const float4*)(base + (size_t)zz * TM * TD);
    v.x += t.x; v.y += t.y; v.z += t.z; v.w += t.w;
  }
  const float* bias = (seg == 0) ? bq : (seg == 1 ? bk : bv);
  float4 b4 = *(const float4*)(bias + c);
  v.x += b4.x; v.y += b4.y; v.z += b4.z; v.w += b4.w;
  if (seg == 0) {
    *(float4*)(qbuf + (size_t)row * TD + c) = v;
  } else {
    const int hh = c / THD, hd = c % THD;
    const int b = row >> 7, sI = row & 127;
    float* dst = (seg == 1) ? sk : sv;
    *(float4*)(dst + (((size_t)(b * TH + hh) * TDEC + sI) * THD + hd)) = v;
  }
}

// ---------------------------------------------------------------------------
// FC1 combine: sum Z partials + bias, exact GELU, write bf16.
// ---------------------------------------------------------------------------
template<int Z>
__global__ void fc1_gelu_kernel(const float* __restrict__ p,
                                const float* __restrict__ bias,
                                short* __restrict__ out)
{
  const int i4 = blockIdx.x * 256 + threadIdx.x;   // over TM*TFFN/4
  const int row = i4 / (TFFN / 4);
  const int c4  = i4 - row * (TFFN / 4);
  const int col = c4 * 4;
  const size_t idx = (size_t)row * TFFN + col;
  float4 v = *(const float4*)(p + idx);
#pragma unroll
  for (int zz = 1; zz < Z; ++zz) {
    float4 t = *(const float4*)(p + (size_t)zz * TM * TFFN + idx);
    v.x += t.x; v.y += t.y; v.z += t.z; v.w += t.w;
  }
  float4 b4 = *(const float4*)(bias + col);
  v.x += b4.x; v.y += b4.y; v.z += b4.z; v.w += b4.w;
  sshort4 o;
  o[0] = f2bf(0.5f * v.x * (1.0f + erff(v.x * 0.70710678118654752f)));
  o[1] = f2bf(0.5f * v.y * (1.0f + erff(v.y * 0.70710678118654752f)));
  o[2] = f2bf(0.5f * v.z * (1.0f + erff(v.z * 0.70710678118654752f)));
  o[3] = f2bf(0.5f * v.w * (1.0f + erff(v.w * 0.70710678118654752f)));
  *(sshort4*)(out + idx) = o;
}

// ---------------------------------------------------------------------------
// Attention: one block per (b,h, 64-q-row tile). K/V bf16 in LDS, scores in
// registers (4 lanes per q-row), softmax via shfl, P bf16 reusing Q LDS.
// ---------------------------------------------------------------------------
template<bool CAUSAL>
__global__ __launch_bounds__(256, 2)
void attn_kernel(const float* __restrict__ q, const float* __restrict__ kc,
                 const float* __restrict__ vc, short* __restrict__ ob)
{
  __shared__ short kb[TS * THD];
  __shared__ short vb[TS * THD];
  __shared__ float qf[64 * 84];
  short* pb = (short*)qf;

  const int tid = threadIdx.x;
  const int bh = blockIdx.x;
  const int b = bh >> 5, h = bh & 31;
  const int r0 = blockIdx.y * 64;

  const size_t cbase = (size_t)bh * TDEC * THD;
  for (int idx = tid; idx < TS * THD; idx += 256) {
    kb[idx] = f2bf(kc[cbase + idx]);
    vb[idx] = f2bf(vc[cbase + idx]);
  }
  for (int idx = tid; idx < 64 * THD; idx += 256) {
    int r = idx / THD, d = idx - r * THD;
    qf[r * 84 + d] = q[(size_t)(b * TS + r0 + r) * TD + h * THD + d];
  }
  __syncthreads();

  const int r = tid >> 2;
  const int quarter = tid & 3;
  const int qi = r0 + r;

  float sc[32];
#pragma unroll 1
  for (int jj = 0; jj < 32; ++jj) {
    int j = quarter + jj * 4;
    if (CAUSAL && j > qi) { sc[jj] = -1e30f; continue; }
    float a = 0.f;
#pragma unroll 8
    for (int d = 0; d < THD; ++d)
      a += qf[r * 84 + d] * bf2f(kb[j * THD + d]);
    sc[jj] = a * 0.11180339887498949f;
  }

  float mx = -1e30f;
#pragma unroll
  for (int jj = 0; jj < 32; ++jj) mx = fmaxf(mx, sc[jj]);
  mx = fmaxf(mx, __shfl_xor(mx, 1));
  mx = fmaxf(mx, __shfl_xor(mx, 2));
  float sum = 0.f;
#pragma unroll
  for (int jj = 0; jj < 32; ++jj) { sc[jj] = __expf(sc[jj] - mx); sum += sc[jj]; }
  sum += __shfl_xor(sum, 1);
  sum += __shfl_xor(sum, 2);
  const float rinv = 1.0f / sum;

  __syncthreads();
#pragma unroll
  for (int jj = 0; jj < 32; ++jj)
    pb[r * TS + quarter + jj * 4] = f2bf(sc[jj] * rinv);
  __syncthreads();

  for (int it = 0; it < 20; ++it) {
    int idx = tid + it * 256;
    int rr = idx / THD, d = idx - rr * THD;
    float a = 0.f;
#pragma unroll 8
    for (int j = 0; j < TS; ++j)
      a += bf2f(pb[rr * TS + j]) * bf2f(vb[j * THD + d]);
    ob[(size_t)(b * TS + r0 + rr) * TD + h * THD + d] = f2bf(a);
  }
}

// ---------------------------------------------------------------------------
// LayerNorm variants
// ---------------------------------------------------------------------------
__global__ __launch_bounds__(256, 4)
void ln_kernel(const float* __restrict__ x, const float* __restrict__ g,
               const float* __restrict__ bb, short* __restrict__ out)
{
  const int row = blockIdx.x;
  const float* xr = x + (size_t)row * TD;
  const int tid = threadIdx.x;
  float vals[10];
  float s = 0.f, ss = 0.f;
#pragma unroll
  for (int it = 0; it < 10; ++it) {
    float v = xr[tid + it * 256];
    vals[it] = v; s += v; ss += v * v;
  }
#pragma unroll
  for (int o = 32; o > 0; o >>= 1) { s += __shfl_xor(s, o); ss += __shfl_xor(ss, o); }
  __shared__ float red[8];
  const int wv = tid >> 6, lane = tid & 63;
  if (lane == 0) { red[wv] = s; red[wv + 4] = ss; }
  __syncthreads();
  s  = red[0] + red[1] + red[2] + red[3];
  ss = red[4] + red[5] + red[6] + red[7];
  const float mu = s * (1.0f / TD);
  const float rstd = rsqrtf(ss * (1.0f / TD) - mu * mu + 1e-5f);
  short* orow = out + (size_t)row * TD;
#pragma unroll
  for (int it = 0; it < 10; ++it) {
    int i = tid + it * 256;
    orow[i] = f2bf((vals[it] - mu) * rstd * g[i] + bb[i]);
  }
}

// x_next = xin + sum_{zz<Z} p[zz] + obias; write x_next (fp32) and LN(x_next) (bf16)
template<int Z>
__global__ __launch_bounds__(256, 4)
void ln_fuse_kernel(const float* __restrict__ xin, const float* __restrict__ p,
                    const float* __restrict__ obias,
                    const float* __restrict__ g, const float* __restrict__ bb,
                    short* __restrict__ hout, float* __restrict__ xout)
{
  const int row = blockIdx.x;
  const int tid = threadIdx.x;
  const size_t base = (size_t)row * TD;
  float vals[10];
  float s = 0.f, ss = 0.f;
#pragma unroll
  for (int it = 0; it < 10; ++it) {
    int i = tid + it * 256;
    float v = xin[base + i] + obias[i];
#pragma unroll
    for (int zz = 0; zz < Z; ++zz)
      v += p[(size_t)zz * TM * TD + base + i];
    vals[it] = v; xout[base + i] = v; s += v; ss += v * v;
  }
#pragma unroll
  for (int o = 32; o > 0; o >>= 1) { s += __shfl_xor(s, o); ss += __shfl_xor(ss, o); }
  __shared__ float red[8];
  const int wv = tid >> 6, lane = tid & 63;
  if (lane == 0) { red[wv] = s; red[wv + 4] = ss; }
  __syncthreads();
  s  = red[0] + red[1] + red[2] + red[3];
  ss = red[4] + red[5] + red[6] + red[7];
  const float mu = s * (1.0f / TD);
  const float rstd = rsqrtf(ss * (1.0f / TD) - mu * mu + 1e-5f);
#pragma unroll
  for (int it = 0; it < 10; ++it) {
    int i = tid + it * 256;
    hout[base + i] = f2bf((vals[it] - mu) * rstd * g[i] + bb[i]);
  }
}

// out = x2 + sum_{zz<Z} p[zz] + bias
template<int Z>
__global__ void fc2_combine_kernel(const float* __restrict__ x2, const float* __restrict__ p,
                                   const float* __restrict__ bias, float* __restrict__ out)
{
  const size_t i = ((size_t)blockIdx.x * 256 + threadIdx.x) * 4;
  const int col = (int)(i % TD);
  float4 v = *(const float4*)(x2 + i);
#pragma unroll
  for (int zz = 0; zz < Z; ++zz) {
    float4 t = *(const float4*)(p + (size_t)zz * TM * TD + i);
    v.x += t.x; v.y += t.y; v.z += t.z; v.w += t.w;
  }
  float4 b4 = *(const float4*)(bias + col);
  v.x += b4.x; v.y += b4.y; v.z += b4.z; v.w += b4.w;
  *(float4*)(out + i) = v;
}

__global__ void cvt_bf16_kernel(const float* __restrict__ in, short* __restrict__ out, int n)
{
  int i = blockIdx.x * 256 + threadIdx.x;
  if (i < n) out[i] = f2bf(in[i]);
}

// Copy cache tail rows (s in [128,256)); float4 granularity.
__global__ void tailcopy_kernel(const float* __restrict__ src, float* __restrict__ dst)
{
  int off4 = blockIdx.x * 256 + threadIdx.x;
  int chunk = blockIdx.y;
  size_t pos = (size_t)chunk * 5120 + 2560 + off4;
  ((float4*)dst)[pos] = ((const float4*)src)[pos];
}

// ---------------------------------------------------------------------------
extern "C" void kernel_launch(void* const* d_in, const int* in_sizes, int n_in,
                              void* d_out, int out_size, void* d_ws, size_t ws_size,
                              hipStream_t stream)
{
  (void)in_sizes; (void)n_in; (void)out_size; (void)ws_size;
  const float* x        = (const float*)d_in[0];
  const float* xa       = (const float*)d_in[1];
  const float* ln1_g    = (const float*)d_in[4];
  const float* ln1_b    = (const float*)d_in[5];
  const float* ln2_g    = (const float*)d_in[6];
  const float* ln2_b    = (const float*)d_in[7];
  const float* ln3_g    = (const float*)d_in[8];
  const float* ln3_b    = (const float*)d_in[9];
  const float* sa_wq    = (const float*)d_in[10];
  const float* sa_wk    = (const float*)d_in[11];
  const float* sa_wv    = (const float*)d_in[12];
  const float* sa_wo    = (const float*)d_in[13];
  const float* sa_bq    = (const float*)d_in[14];
  const float* sa_bk    = (const float*)d_in[15];
  const float* sa_bv    = (const float*)d_in[16];
  const float* sa_bo    = (const float*)d_in[17];
  const float* ca_wq    = (const float*)d_in[18];
  const float* ca_wk    = (const float*)d_in[19];
  const float* ca_wv    = (const float*)d_in[20];
  const float* ca_wo    = (const float*)d_in[21];
  const float* ca_bq    = (const float*)d_in[22];
  const float* ca_bk    = (const float*)d_in[23];
  const float* ca_bv    = (const float*)d_in[24];
  const float* ca_bo    = (const float*)d_in[25];
  const float* cache_sk = (const float*)d_in[26];
  const float* cache_sv = (const float*)d_in[27];
  const float* cache_ck = (const float*)d_in[28];
  const float* cache_cv = (const float*)d_in[29];
  const float* fc1_w    = (const float*)d_in[30];
  const float* fc1_b    = (const float*)d_in[31];
  const float* fc2_w    = (const float*)d_in[32];
  const float* fc2_b    = (const float*)d_in[33];

  float* out_x  = (float*)d_out;
  float* out_sk = out_x + (size_t)TM * TD;
  float* out_sv = out_sk + CACHE_N;
  float* out_ck = out_sv + CACHE_N;
  float* out_cv = out_ck + CACHE_N;

  char* w = (char*)d_ws;
  short* h_b   = (short*)w; w += (size_t)TM * TD * 2;
  short* xa_b  = (short*)w; w += (size_t)TM * TD * 2;
  short* o_b   = (short*)w; w += (size_t)TM * TD * 2;
  short* ffn_b = (short*)w; w += (size_t)TM * TFFN * 2;
  float* qbuf  = (float*)w; w += (size_t)TM * TD * 4;
  float* x1    = (float*)w; w += (size_t)TM * TD * 4;
  float* x2    = (float*)w; w += (size_t)TM * TD * 4;
  float* pbuf  = (float*)w; w += (size_t)TM * TD * 4 * 12;   // 12 z-slices (max: QKV 3 segs x z=4)

  const dim3 blk(256);
  const dim3 gAttn(TB * TH, 2);

  // prep
  cvt_bf16_kernel<<<dim3(TM * TD / 256), blk, 0, stream>>>(xa, xa_b, TM * TD);
  tailcopy_kernel<<<dim3(10, TB * TH), blk, 0, stream>>>(cache_sk, out_sk);
  tailcopy_kernel<<<dim3(10, TB * TH), blk, 0, stream>>>(cache_sv, out_sv);
  tailcopy_kernel<<<dim3(10, TB * TH), blk, 0, stream>>>(cache_ck, out_ck);
  tailcopy_kernel<<<dim3(10, TB * TH), blk, 0, stream>>>(cache_cv, out_cv);

  // ---- self-attention ----
  ln_kernel<<<dim3(TM), blk, 0, stream>>>(x, ln1_g, ln1_b, h_b);
  {
    GArgs a{};
    a.A[0] = h_b; a.B[0] = sa_wq; a.outf[0] = pbuf;
    a.A[1] = h_b; a.B[1] = sa_wk; a.outf[1] = pbuf + (size_t)4 * TM * TD;
    a.A[2] = h_b; a.B[2] = sa_wv; a.outf[2] = pbuf + (size_t)8 * TM * TD;
    a.tilesPerSeg = 20; a.nx = 60; a.N = TD; a.lda = TD; a.Kc = TD / 4;
    gemmF<<<dim3(960), blk, 0, stream>>>(a);
  }
  qkv_combine_kernel<4><<<dim3(TM * 7680 / 4 / 256), blk, 0, stream>>>(
      pbuf, sa_bq, sa_bk, sa_bv, qbuf, out_sk, out_sv);
  attn_kernel<true><<<gAttn, blk, 0, stream>>>(qbuf, out_sk, out_sv, o_b);
  {
    GArgs a{};
    a.A[0] = o_b; a.B[0] = sa_wo; a.outf[0] = pbuf;
    a.tilesPerSeg = 20; a.nx = 20; a.N = TD; a.lda = TD; a.Kc = TD / 8;
    gemmF<<<dim3(640), blk, 0, stream>>>(a);
  }
  ln_fuse_kernel<8><<<dim3(TM), blk, 0, stream>>>(x, pbuf, sa_bo, ln2_g, ln2_b, h_b, x1);

  // ---- cross-attention ----
  {
    GArgs a{};
    a.A[0] = h_b;  a.B[0] = ca_wq; a.outf[0] = pbuf;
    a.A[1] = xa_b; a.B[1] = ca_wk; a.outf[1] = pbuf + (size_t)4 * TM * TD;
    a.A[2] = xa_b; a.B[2] = ca_wv; a.outf[2] = pbuf + (size_t)8 * TM * TD;
    a.tilesPerSeg = 20; a.nx = 60; a.N = TD; a.lda = TD; a.Kc = TD / 4;
    gemmF<<<dim3(960), blk, 0, stream>>>(a);
  }
  qkv_combine_kernel<4><<<dim3(TM * 7680 / 4 / 256), blk, 0, stream>>>(
      pbuf, ca_bq, ca_bk, ca_bv, qbuf, out_ck, out_cv);
  attn_kernel<false><<<gAttn, blk, 0, stream>>>(qbuf, out_ck, out_cv, o_b);
  {
    GArgs a{};
    a.A[0] = o_b; a.B[0] = ca_wo; a.outf[0] = pbuf;
    a.tilesPerSeg = 20; a.nx = 20; a.N = TD; a.lda = TD; a.Kc = TD / 8;
    gemmF<<<dim3(640), blk, 0, stream>>>(a);
  }
  ln_fuse_kernel<8><<<dim3(TM), blk, 0, stream>>>(x1, pbuf, ca_bo, ln3_g, ln3_b, h_b, x2);

  // ---- MLP ----
  {
    GArgs a{};
    a.A[0] = h_b; a.B[0] = fc1_w; a.outf[0] = pbuf;
    a.tilesPerSeg = 80; a.nx = 80; a.N = TFFN; a.lda = TD; a.Kc = TD / 2;
    gemmF<<<dim3(640), blk, 0, stream>>>(a);
  }
  fc1_gelu_kernel<2><<<dim3(TM * TFFN / 4 / 256), blk, 0, stream>>>(pbuf, fc1_b, ffn_b);
  {
    GArgs a{};
    a.A[0] = ffn_b; a.B[0] = fc2_w; a.outf[0] = pbuf;
    a.tilesPerSeg = 20; a.nx = 20; a.N = TD; a.lda = TFFN; a.Kc = TFFN / 8;
    gemmF<<<dim3(640), blk, 0, stream>>>(a);
  }
  fc2_combine_kernel<8><<<dim3(TM * TD / 4 / 256), blk, 0, stream>>>(x2, pbuf, fc2_b, out_x);
}